// Round 1
// baseline (391.892 us; speedup 1.0000x reference)
//
#include <hip/hip_runtime.h>
#include <math.h>

constexpr int M  = 64;      // rows of phi / Y
constexpr int NR = 256;     // rows of X (cols of phi)
constexpr int NC = 131072;  // columns of X / Y
constexpr float THR = 0.1f;

__global__ __launch_bounds__(256)
void k_copy_phi(const float* __restrict__ phi, float* __restrict__ out)
{
    int i = blockIdx.x * 256 + threadIdx.x;
    out[i] = phi[i];
}

// Each thread owns 2 columns: j0 = bx*512 + tid, j1 = j0 + 256.
// phiT in LDS laid out [rr][mm] (rr = X-row 0..255, mm = Y-row 0..63) so both
// phases read 64 contiguous floats per row -> ds_read_b128, wave-uniform
// address -> LDS broadcast (no bank conflicts).
__global__ __launch_bounds__(256, 2)
void k_fused(const float* __restrict__ phi,
             const float* __restrict__ X,
             const float* __restrict__ Y,
             const float* __restrict__ step,
             const int*   __restrict__ idxp,
             float* __restrict__ outX)
{
    const int k   = idxp[0] + 1;
    const int tid = threadIdx.x;
    const int j0  = blockIdx.x * 512 + tid;
    const int j1  = j0 + 256;

    if (blockIdx.x * 512 >= k) {          // pure-copy block (uniform branch)
        #pragma unroll 4
        for (int rr = 0; rr < NR; ++rr) {
            outX[rr * NC + j0] = X[rr * NC + j0];
            outX[rr * NC + j1] = X[rr * NC + j1];
        }
        return;
    }

    __shared__ float phiT[NR * M];        // 64 KiB
    for (int i = tid; i < M * NR; i += 256) {
        int mm = i >> 8;                  // phi row
        int rr = i & (NR - 1);            // phi col
        phiT[rr * M + mm] = phi[i];
    }
    __syncthreads();

    const float s  = step[0];
    const bool a0 = (j0 < k), a1 = (j1 < k);

    float r0[M], r1[M];
    #pragma unroll
    for (int mm = 0; mm < M; ++mm) { r0[mm] = 0.f; r1[mm] = 0.f; }

    // ---------------- phase 1 : r = phi @ x ----------------
    float xa[4][2];
    #pragma unroll
    for (int q = 0; q < 4; ++q) {
        xa[q][0] = X[q * NC + j0];
        xa[q][1] = X[q * NC + j1];
    }
    for (int rr = 0; rr < NR; rr += 4) {
        const int pr = (rr + 4) & (NR - 1);   // masked prefetch (last iter wraps, discarded)
        float xn[4][2];
        #pragma unroll
        for (int q = 0; q < 4; ++q) {
            xn[q][0] = X[(pr + q) * NC + j0];
            xn[q][1] = X[(pr + q) * NC + j1];
        }
        #pragma unroll
        for (int q = 0; q < 4; ++q) {
            #pragma unroll
            for (int mm = 0; mm < M; ++mm) {
                float p = phiT[(rr + q) * M + mm];
                r0[mm] = fmaf(p, xa[q][0], r0[mm]);
                r1[mm] = fmaf(p, xa[q][1], r1[mm]);
            }
        }
        #pragma unroll
        for (int q = 0; q < 4; ++q) { xa[q][0] = xn[q][0]; xa[q][1] = xn[q][1]; }
    }

    // ---------------- r = Y - r ----------------
    #pragma unroll
    for (int mm = 0; mm < M; ++mm) {
        r0[mm] = Y[mm * NC + j0] - r0[mm];
        r1[mm] = Y[mm * NC + j1] - r1[mm];
    }

    // ---------------- phase 2 : u = x + s*(phiT @ r) ----------------
    #pragma unroll
    for (int q = 0; q < 4; ++q) {
        xa[q][0] = X[q * NC + j0];
        xa[q][1] = X[q * NC + j1];
    }
    for (int rr = 0; rr < NR; rr += 4) {
        const int pr = (rr + 4) & (NR - 1);
        float xn[4][2];
        #pragma unroll
        for (int q = 0; q < 4; ++q) {
            xn[q][0] = X[(pr + q) * NC + j0];
            xn[q][1] = X[(pr + q) * NC + j1];
        }
        float u[4][2][2];
        #pragma unroll
        for (int q = 0; q < 4; ++q) {
            u[q][0][0] = 0.f; u[q][0][1] = 0.f;
            u[q][1][0] = 0.f; u[q][1][1] = 0.f;
        }
        #pragma unroll
        for (int q = 0; q < 4; ++q) {
            #pragma unroll
            for (int mm = 0; mm < M; mm += 2) {   // 2 partial sums per output: break latency chain
                float p0 = phiT[(rr + q) * M + mm];
                float p1 = phiT[(rr + q) * M + mm + 1];
                u[q][0][0] = fmaf(p0, r0[mm],     u[q][0][0]);
                u[q][0][1] = fmaf(p1, r0[mm + 1], u[q][0][1]);
                u[q][1][0] = fmaf(p0, r1[mm],     u[q][1][0]);
                u[q][1][1] = fmaf(p1, r1[mm + 1], u[q][1][1]);
            }
        }
        #pragma unroll
        for (int q = 0; q < 4; ++q) {
            float v0 = fmaf(s, u[q][0][0] + u[q][0][1], xa[q][0]);
            float v1 = fmaf(s, u[q][1][0] + u[q][1][1], xa[q][1]);
            v0 = (fabsf(v0) > THR) ? v0 : 0.f;
            v1 = (fabsf(v1) > THR) ? v1 : 0.f;
            outX[(rr + q) * NC + j0] = a0 ? v0 : xa[q][0];   // j>=k lanes: plain copy
            outX[(rr + q) * NC + j1] = a1 ? v1 : xa[q][1];
        }
        #pragma unroll
        for (int q = 0; q < 4; ++q) { xa[q][0] = xn[q][0]; xa[q][1] = xn[q][1]; }
    }
}

extern "C" void kernel_launch(void* const* d_in, const int* in_sizes, int n_in,
                              void* d_out, int out_size, void* d_ws, size_t ws_size,
                              hipStream_t stream)
{
    const float* phi  = (const float*)d_in[0];
    const float* X    = (const float*)d_in[1];
    const float* Y    = (const float*)d_in[2];
    const float* step = (const float*)d_in[3];
    const int*   idx  = (const int*)d_in[4];
    float* out = (float*)d_out;

    k_copy_phi<<<(M * NR) / 256, 256, 0, stream>>>(phi, out);
    k_fused<<<NC / 512, 256, 0, stream>>>(phi, X, Y, step, idx, out + M * NR);
}

// Round 2
// 323.848 us; speedup vs baseline: 1.2101x; 1.2101x over previous
//
#include <hip/hip_runtime.h>
#include <math.h>

constexpr int M   = 64;       // rows of phi / Y
constexpr int NR  = 256;      // rows of X
constexpr int KK  = NR + M;   // 320: stacked K dim  [W | Z] · [X ; Y]
constexpr int NC  = 131072;   // columns
constexpr int BN  = 64;       // columns per block
constexpr float THR = 0.1f;

typedef __bf16 bf16x8 __attribute__((ext_vector_type(8)));
typedef float  f32x4  __attribute__((ext_vector_type(4)));

static __device__ __forceinline__ unsigned short f2bf(float f) {
    unsigned int u = __float_as_uint(f);
    u += 0x7FFFu + ((u >> 16) & 1u);        // round-to-nearest-even
    return (unsigned short)(u >> 16);
}

__global__ __launch_bounds__(256)
void k_copy_phi(const float* __restrict__ phi, float* __restrict__ out)
{
    int i = blockIdx.x * 256 + threadIdx.x;
    out[i] = phi[i];
}

// Build A = [ I - s*phi^T*phi  |  s*phi^T ]  (256 x 320, bf16 row-major) in ws.
// Block i computes row i.
__global__ __launch_bounds__(256)
void k_prep(const float* __restrict__ phi, const float* __restrict__ step,
            unsigned short* __restrict__ A)
{
    __shared__ float ph[M * NR];            // 64 KiB, phi row-major 64x256
    const int i = blockIdx.x, j = threadIdx.x;
    for (int t = j; t < M * NR; t += 256) ph[t] = phi[t];
    __syncthreads();
    const float s = step[0];
    float d = 0.f;
    #pragma unroll
    for (int m = 0; m < M; ++m)
        d = fmaf(ph[m * NR + i], ph[m * NR + j], d);
    float w = ((i == j) ? 1.f : 0.f) - s * d;
    A[i * KK + j] = f2bf(w);
    if (j < M) A[i * KK + NR + j] = f2bf(s * ph[j * NR + i]);
}

// U = A[256x320] * [X;Y][320xN], threshold, copy for cols >= k.
// Block: 256 thr = 4 waves; BN=64 cols; wave w owns U rows 64w..64w+63.
// LDS B layout (bf16, fragment-major, pad 40): elem(kb,n,kl) = kb*2560 + n*40 + kl
//   -> fragment read (n=lane&15 per n-tile, k=quad*8+j) is a 16B-aligned b128.
__global__ __launch_bounds__(256, 3)
void k_gemm(const unsigned short* __restrict__ A,
            const float* __restrict__ X,
            const float* __restrict__ Y,
            const int*   __restrict__ idxp,
            float* __restrict__ outX)
{
    const int k   = idxp[0] + 1;
    const int n0  = blockIdx.x * BN;
    const int tid = threadIdx.x;

    if (n0 >= k) {                           // pure-copy fast path
        const int c4 = tid & 15, rg = tid >> 4;
        #pragma unroll 4
        for (int r = rg; r < NR; r += 16) {
            const float4* src = (const float4*)(X + (size_t)r * NC + n0);
            float4*       dst = (float4*)(outX + (size_t)r * NC + n0);
            dst[c4] = src[c4];
        }
        return;
    }

    __shared__ unsigned int Bu32[10 * 2560 / 2];   // 51200 B as packed bf16 pairs

    // ---- stage [X;Y] tile -> bf16 LDS ----
    {
        const int n = tid & 63, slot = tid >> 6;
        for (int p = slot; p < KK / 2; p += 4) {
            const int r = p << 1;            // even row; pairs never cross X/Y seam (256 even)
            const float* s0 = (r < NR) ? (X + (size_t)r * NC)
                                       : (Y + (size_t)(r - NR) * NC);
            const float* s1 = (r < NR) ? (X + (size_t)(r + 1) * NC)
                                       : (Y + (size_t)(r + 1 - NR) * NC);
            float v0 = s0[n0 + n], v1 = s1[n0 + n];
            const int kb = r >> 5, kl = r & 31;
            Bu32[(kb * 2560 + n * 40 + kl) >> 1] =
                (unsigned int)f2bf(v0) | ((unsigned int)f2bf(v1) << 16);
        }
    }
    __syncthreads();

    const int lane = tid & 63, wave = tid >> 6;
    const int quad = lane >> 4, nlo = lane & 15;
    const int mbase = wave * 64;

    f32x4 acc[4][4];
    #pragma unroll
    for (int mt = 0; mt < 4; ++mt)
        #pragma unroll
        for (int nt = 0; nt < 4; ++nt)
            acc[mt][nt] = (f32x4){0.f, 0.f, 0.f, 0.f};

    const unsigned short* Abase = A + (size_t)(mbase + nlo) * KK + quad * 8;
    const unsigned int*   Bbase = Bu32 + ((nlo * 40 + quad * 8) >> 1);

    #pragma unroll 2
    for (int kb = 0; kb < 10; ++kb) {
        bf16x8 afr[4], bfr[4];
        #pragma unroll
        for (int mt = 0; mt < 4; ++mt)
            afr[mt] = *(const bf16x8*)(Abase + (size_t)mt * 16 * KK + kb * 32);
        #pragma unroll
        for (int nt = 0; nt < 4; ++nt)
            bfr[nt] = *(const bf16x8*)(Bbase + (kb * 2560 + nt * 16 * 40) / 2);
        #pragma unroll
        for (int mt = 0; mt < 4; ++mt)
            #pragma unroll
            for (int nt = 0; nt < 4; ++nt)
                acc[mt][nt] = __builtin_amdgcn_mfma_f32_16x16x32_bf16(
                    afr[mt], bfr[nt], acc[mt][nt], 0, 0, 0);
    }

    // ---- epilogue: threshold + boundary copy + store ----
    const bool boundary = (n0 + BN > k);
    #pragma unroll
    for (int mt = 0; mt < 4; ++mt) {
        #pragma unroll
        for (int nt = 0; nt < 4; ++nt) {
            const int col = n0 + nt * 16 + nlo;
            #pragma unroll
            for (int reg = 0; reg < 4; ++reg) {
                const int row = mbase + mt * 16 + quad * 4 + reg;
                float v = acc[mt][nt][reg];
                v = (fabsf(v) > THR) ? v : 0.f;
                if (boundary && col >= k) v = X[(size_t)row * NC + col];
                outX[(size_t)row * NC + col] = v;
            }
        }
    }
}

extern "C" void kernel_launch(void* const* d_in, const int* in_sizes, int n_in,
                              void* d_out, int out_size, void* d_ws, size_t ws_size,
                              hipStream_t stream)
{
    const float* phi  = (const float*)d_in[0];
    const float* X    = (const float*)d_in[1];
    const float* Y    = (const float*)d_in[2];
    const float* step = (const float*)d_in[3];
    const int*   idx  = (const int*)d_in[4];
    float* out = (float*)d_out;
    unsigned short* A = (unsigned short*)d_ws;   // 256*320*2 = 160 KiB

    k_copy_phi<<<(M * NR) / 256, 256, 0, stream>>>(phi, out);
    k_prep<<<NR, 256, 0, stream>>>(phi, step, A);
    k_gemm<<<NC / BN, 256, 0, stream>>>(A, X, Y, idx, out + M * NR);
}